// Round 11
// baseline (95.223 us; speedup 1.0000x reference)
//
#include <hip/hip_runtime.h>
#include <math.h>

#define NQ 512
#define NC 8000
#define DNUM 6
#define NBINS 50
#define DCAT 20
#define DENC 26      // DNUM + DCAT
#define DOUT 10
#define CHUNK 1000
#define NCHUNK 8
#define PSTRIDE 12   // per-(q,chunk) partial: 10 class sums, s, m

// ---------- encode ----------
// G_f(v) = sum_j ceil((v - u_fj*delta_fj)/delta_fj). Each per-bin map is
// fp-monotone in v (sub, div-by-positive, ceil), so all 50 bin diffs for a
// feature share sign => sum_j |bin_j(x)-bin_j(c)| == |G_f(x)-G_f(c)| exactly
// (integer-valued floats, sums << 2^24). 320-dim L1 -> 26-dim L1.
__global__ void encode(const float* __restrict__ c_num, const float* __restrict__ c_cat,
                       const float* __restrict__ x_num, const float* __restrict__ x_cat,
                       const float* __restrict__ delta, const float* __restrict__ u,
                       float* __restrict__ cEnc, float* __restrict__ qEnc) {
    int i = blockIdx.x * 256 + threadIdx.x;
    const int nA = (NC + NQ) * DNUM;          // 51072
    const int nB = (NC + NQ) * DCAT;          // 170240
    if (i < nA) {
        int f = i % DNUM, p = i / DNUM;
        bool is_c = p < NC;
        int idx = is_c ? p : p - NC;
        float v = (is_c ? c_num : x_num)[idx * DNUM + f];
        float g = 0.f;
        for (int j = 0; j < NBINS; ++j) {
            // exact reference op order: scaled_u = u*delta; ceil((v - scaled_u)/delta)
            float dl = delta[f * NBINS + j];
            float sc = u[f * NBINS + j] * dl;
            g += ceilf((v - sc) / dl);
        }
        if (is_c) cEnc[f * NC + idx] = g;
        else      qEnc[f * NQ + idx] = g;
    } else if (i < nA + nB) {
        int i2 = i - nA;
        int k = i2 % DCAT, p = i2 / DCAT;
        bool is_c = p < NC;
        int idx = is_c ? p : p - NC;
        float v = (is_c ? c_cat : x_cat)[idx * DCAT + k];
        if (is_c) cEnc[(DNUM + k) * NC + idx] = v;
        else      qEnc[(DNUM + k) * NQ + idx] = v;
    }
}

// ---------- main: block = (2 queries, ONE 1000-candidate chunk) ----------
// grid (8, 256) = 2048 blocks x 256 thr -> 4-8 blocks/CU (16-32 waves/CU).
// bx = chunk: all 256 blocks sharing a chunk slice map to one XCD's L2.
// d-loop: pure VALU + coalesced float4 loads + hoisted s_loads of qEnc.
// ALL cross-lane reduction happens exactly once, at the end. Arithmetic is
// op-for-op R8's reduce_k (absmax 0): block min -> exp(m-d) -> butterflies.
__global__ __launch_bounds__(256) void nca_chunk(
    const float* __restrict__ cEnc, const float* __restrict__ qEnc,
    const int* __restrict__ cy, float* __restrict__ parts) {
    __shared__ float wm[4][2];
    __shared__ float wsum[4][2];
    __shared__ float wcls[4][2 * DOUT];

    const int tid = threadIdx.x;
    const int chunk = blockIdx.x;
    const int q0 = blockIdx.y * 2;
    const int lane = tid & 63, wave = tid >> 6;
    const bool act = tid < CHUNK / 4;                       // 250
    const int base = chunk * CHUNK + (act ? 4 * tid : CHUNK - 4);

    float a[2][4] = {{0.f, 0.f, 0.f, 0.f}, {0.f, 0.f, 0.f, 0.f}};
#pragma unroll
    for (int d = 0; d < DENC; ++d) {
        float4 cv = *(const float4*)(cEnc + (size_t)d * NC + base);
        float x0 = qEnc[d * NQ + q0];        // wave-uniform -> s_load
        float x1 = qEnc[d * NQ + q0 + 1];
        a[0][0] += fabsf(cv.x - x0); a[0][1] += fabsf(cv.y - x0);
        a[0][2] += fabsf(cv.z - x0); a[0][3] += fabsf(cv.w - x0);
        a[1][0] += fabsf(cv.x - x1); a[1][1] += fabsf(cv.y - x1);
        a[1][2] += fabsf(cv.z - x1); a[1][3] += fabsf(cv.w - x1);
    }

    // ---- block min per q ----
    float m0 = act ? fminf(fminf(a[0][0], a[0][1]), fminf(a[0][2], a[0][3])) : INFINITY;
    float m1 = act ? fminf(fminf(a[1][0], a[1][1]), fminf(a[1][2], a[1][3])) : INFINITY;
#pragma unroll
    for (int sh = 32; sh >= 1; sh >>= 1) {
        m0 = fminf(m0, __shfl_xor(m0, sh));
        m1 = fminf(m1, __shfl_xor(m1, sh));
    }
    if (lane == 0) { wm[wave][0] = m0; wm[wave][1] = m1; }
    __syncthreads();
    const float mq0 = fminf(fminf(wm[0][0], wm[1][0]), fminf(wm[2][0], wm[3][0]));
    const float mq1 = fminf(fminf(wm[0][1], wm[1][1]), fminf(wm[2][1], wm[3][1]));

    // ---- per-thread partials ----
    float cls[2 * DOUT];
#pragma unroll
    for (int k = 0; k < 2 * DOUT; ++k) cls[k] = 0.f;
    float s0 = 0.f, s1 = 0.f;
    if (act) {
        int4 y = *(const int4*)(cy + base);
        float e00 = __expf(-a[0][0]), e01 = __expf(-a[0][1]),
              e02 = __expf(-a[0][2]), e03 = __expf(-a[0][3]);
        float e10 = __expf(-a[1][0]), e11 = __expf(-a[1][1]),
              e12 = __expf(-a[1][2]), e13 = __expf(-a[1][3]);
#pragma unroll
        for (int k = 0; k < DOUT; ++k) {
            cls[k]        = (y.x == k ? e00 : 0.f) + (y.y == k ? e01 : 0.f) +
                            (y.z == k ? e02 : 0.f) + (y.w == k ? e03 : 0.f);
            cls[DOUT + k] = (y.x == k ? e10 : 0.f) + (y.y == k ? e11 : 0.f) +
                            (y.z == k ? e12 : 0.f) + (y.w == k ? e13 : 0.f);
        }
        s0 = __expf(mq0 - a[0][0]) + __expf(mq0 - a[0][1]) +
             __expf(mq0 - a[0][2]) + __expf(mq0 - a[0][3]);
        s1 = __expf(mq1 - a[1][0]) + __expf(mq1 - a[1][1]) +
             __expf(mq1 - a[1][2]) + __expf(mq1 - a[1][3]);
    }

    // ---- butterflies (22 independent chains) ----
#pragma unroll
    for (int sh = 32; sh >= 1; sh >>= 1) {
        s0 += __shfl_xor(s0, sh);
        s1 += __shfl_xor(s1, sh);
    }
#pragma unroll
    for (int k = 0; k < 2 * DOUT; ++k) {
#pragma unroll
        for (int sh = 32; sh >= 1; sh >>= 1) cls[k] += __shfl_xor(cls[k], sh);
    }
    if (lane == 0) {
        wsum[wave][0] = s0; wsum[wave][1] = s1;
#pragma unroll
        for (int k = 0; k < 2 * DOUT; ++k) wcls[wave][k] = cls[k];
    }
    __syncthreads();

    // ---- cross-wave combine + write per-(q,chunk) partials ----
    if (tid < 2) {
        float S = wsum[0][tid] + wsum[1][tid] + wsum[2][tid] + wsum[3][tid];
        float* p = parts + ((size_t)(q0 + tid) * NCHUNK + chunk) * PSTRIDE;
        p[10] = S;
        p[11] = (tid == 0) ? mq0 : mq1;
    }
    if (tid < 2 * DOUT) {
        int q = tid / DOUT, k = tid % DOUT;
        float s = wcls[0][tid] + wcls[1][tid] + wcls[2][tid] + wcls[3][tid];
        parts[((size_t)(q0 + q) * NCHUNK + chunk) * PSTRIDE + k] = s;
    }
}

// ---------- finalize (R8-proven) ----------
__global__ void finalize(const float* __restrict__ parts, float* __restrict__ out) {
    int q = blockIdx.x * 256 + threadIdx.x;
    if (q >= NQ) return;
    float logits[DOUT];
#pragma unroll
    for (int k = 0; k < DOUT; ++k) logits[k] = 0.f;
    float lse = 0.f;
#pragma unroll
    for (int ch = 0; ch < NCHUNK; ++ch) {
        const float* p = parts + ((size_t)q * NCHUNK + ch) * PSTRIDE;
#pragma unroll
        for (int k = 0; k < DOUT; ++k) logits[k] += p[k];
        lse += logf(p[10]) - p[11];       // log(sum exp(m-d)) - m
    }
#pragma unroll
    for (int k = 0; k < DOUT; ++k)
        out[q * DOUT + k] = logf(logits[k] + 1e-8f) - lse;
}

extern "C" void kernel_launch(void* const* d_in, const int* in_sizes, int n_in,
                              void* d_out, int out_size, void* d_ws, size_t ws_size,
                              hipStream_t stream) {
    const float* x_num = (const float*)d_in[0];
    const float* x_cat = (const float*)d_in[1];
    const float* c_num = (const float*)d_in[2];
    const float* c_cat = (const float*)d_in[3];
    const int*   c_y   = (const int*)d_in[4];
    const float* delta = (const float*)d_in[5];
    const float* u     = (const float*)d_in[6];

    float* ws = (float*)d_ws;
    float* cEnc = ws;                             // 26*8000 = 208,000 floats
    float* qEnc = cEnc + (size_t)DENC * NC;       // 26*512  = 13,312
    float* parts = qEnc + (size_t)DENC * NQ;      // 512*8*12 = 49,152

    const int total = (NC + NQ) * DENC;           // 221,312
    encode<<<(total + 255) / 256, 256, 0, stream>>>(
        c_num, c_cat, x_num, x_cat, delta, u, cEnc, qEnc);
    nca_chunk<<<dim3(NCHUNK, NQ / 2), 256, 0, stream>>>(cEnc, qEnc, c_y, parts);
    finalize<<<(NQ + 255) / 256, 256, 0, stream>>>(parts, (float*)d_out);
}

// Round 13
// 94.410 us; speedup vs baseline: 1.0086x; 1.0086x over previous
//
#include <hip/hip_runtime.h>
#include <math.h>

#define NQ 512
#define NC 8000
#define DNUM 6
#define NBINS 50
#define DCAT 20
#define DENC 26      // DNUM + DCAT
#define DOUT 10
#define CHUNK 1000
#define NCHUNK 8

// ---------- encode ----------
// G_f(v) = sum_j ceil((v - u_fj*delta_fj)/delta_fj). Each per-bin map is
// fp-monotone in v (sub, div-by-positive, ceil), so all 50 bin diffs for a
// feature share sign => sum_j |bin_j(x)-bin_j(c)| == |G_f(x)-G_f(c)| exactly
// (integer-valued floats, sums << 2^24). 320-dim L1 -> 26-dim L1.
__global__ void encode(const float* __restrict__ c_num, const float* __restrict__ c_cat,
                       const float* __restrict__ x_num, const float* __restrict__ x_cat,
                       const float* __restrict__ delta, const float* __restrict__ u,
                       float* __restrict__ cEnc, float* __restrict__ qEnc) {
    int i = blockIdx.x * 256 + threadIdx.x;
    const int nA = (NC + NQ) * DNUM;          // 51072
    const int nB = (NC + NQ) * DCAT;          // 170240
    if (i < nA) {
        int f = i % DNUM, p = i / DNUM;
        bool is_c = p < NC;
        int idx = is_c ? p : p - NC;
        float v = (is_c ? c_num : x_num)[idx * DNUM + f];
        float g = 0.f;
        for (int j = 0; j < NBINS; ++j) {
            // exact reference op order: scaled_u = u*delta; ceil((v - scaled_u)/delta)
            float dl = delta[f * NBINS + j];
            float sc = u[f * NBINS + j] * dl;
            g += ceilf((v - sc) / dl);
        }
        if (is_c) cEnc[f * NC + idx] = g;
        else      qEnc[f * NQ + idx] = g;
    } else if (i < nA + nB) {
        int i2 = i - nA;
        int k = i2 % DCAT, p = i2 / DCAT;
        bool is_c = p < NC;
        int idx = is_c ? p : p - NC;
        float v = (is_c ? c_cat : x_cat)[idx * DCAT + k];
        if (is_c) cEnc[(DNUM + k) * NC + idx] = v;
        else      qEnc[(DNUM + k) * NQ + idx] = v;
    }
}

// ---------- all-in-one: block = 2 queries x all 8000 candidates ----------
// R10 base (best measured: 92.4 total) + two latency cuts:
//  (1) online-softmax merge: per chunk ONE 6-step (m,s) butterfly instead of
//      min-chain -> dependent sum-chain (12 serial DS latencies -> 6).
//      Wave-final s = sum exp(m_wave - d), identical semantics to R10.
//  (2) double-buffered chunk prefetch: next chunk's 26 float2 loads issue
//      before the current chunk's reduction, hiding L2 latency.
__global__ __launch_bounds__(512) void nca_all(
    const float* __restrict__ cEnc, const float* __restrict__ qEnc,
    const int* __restrict__ cy, float* __restrict__ out) {
    __shared__ float xs[DENC * 2];              // 52
    __shared__ float ms_parts[NCHUNK * 8 * 4];  // [chunk][wave][m0,s0,m1,s1]
    __shared__ float cls_parts[8][2 * DOUT];    // [wave][q*10+k]
    __shared__ float tmp[2][NCHUNK];
    __shared__ float lse_sh[2];

    const int tid = threadIdx.x;
    const int q0 = blockIdx.x * 2;
    if (tid < DENC * 2) {
        int d = tid >> 1, q = tid & 1;
        xs[tid] = qEnc[d * NQ + q0 + q];
    }
    __syncthreads();

    float xr0[DENC], xr1[DENC];
#pragma unroll
    for (int d = 0; d < DENC; ++d) { xr0[d] = xs[2 * d]; xr1[d] = xs[2 * d + 1]; }

    const bool act = tid < 500;                 // 500 * 2 = 1000 candidates
    const int cl = act ? 2 * tid : 996;         // clamp inactive to safe addr
    const int lane = tid & 63, wave = tid >> 6;

    float cls[2 * DOUT];                        // per-thread class sums, all chunks
#pragma unroll
    for (int k = 0; k < 2 * DOUT; ++k) cls[k] = 0.f;

    auto process = [&](const float2* cv, int chunk) {
        float a00 = 0.f, a01 = 0.f, a10 = 0.f, a11 = 0.f;   // a[q][cand]
#pragma unroll
        for (int d = 0; d < DENC; ++d) {
            a00 += fabsf(cv[d].x - xr0[d]); a01 += fabsf(cv[d].y - xr0[d]);
            a10 += fabsf(cv[d].x - xr1[d]); a11 += fabsf(cv[d].y - xr1[d]);
        }

        // ---- lse: single online-softmax butterfly per q ----
        float m0, s0, m1, s1;
        if (act) {
            m0 = fminf(a00, a01);
            s0 = __expf(m0 - a00) + __expf(m0 - a01);
            m1 = fminf(a10, a11);
            s1 = __expf(m1 - a10) + __expf(m1 - a11);
        } else {
            m0 = 1e30f; s0 = 0.f; m1 = 1e30f; s1 = 0.f;   // finite: avoids inf-inf NaN
        }
#pragma unroll
        for (int sh = 32; sh >= 1; sh >>= 1) {
            float mo0 = __shfl_xor(m0, sh), so0 = __shfl_xor(s0, sh);
            float mo1 = __shfl_xor(m1, sh), so1 = __shfl_xor(s1, sh);
            float M0 = fminf(m0, mo0);
            float M1 = fminf(m1, mo1);
            s0 = s0 * __expf(M0 - m0) + so0 * __expf(M0 - mo0);
            s1 = s1 * __expf(M1 - m1) + so1 * __expf(M1 - mo1);
            m0 = M0; m1 = M1;
        }
        if (lane == 0) {
            float* p = ms_parts + (chunk * 8 + wave) * 4;
            p[0] = m0; p[1] = s0; p[2] = m1; p[3] = s1;
        }

        // ---- class sums accumulate in registers across chunks ----
        if (act) {
            int2 y = *(const int2*)(cy + chunk * CHUNK + cl);
            float e00 = __expf(-a00), e01 = __expf(-a01);
            float e10 = __expf(-a10), e11 = __expf(-a11);
#pragma unroll
            for (int k = 0; k < DOUT; ++k) {
                cls[k]        += (y.x == k ? e00 : 0.f) + (y.y == k ? e01 : 0.f);
                cls[DOUT + k] += (y.x == k ? e10 : 0.f) + (y.y == k ? e11 : 0.f);
            }
        }
    };

    const float* cp = cEnc + cl;
    float2 bufA[DENC], bufB[DENC];
#pragma unroll
    for (int d = 0; d < DENC; ++d)
        bufA[d] = *(const float2*)(cp + (size_t)d * NC);          // chunk 0

#pragma unroll
    for (int pair = 0; pair < NCHUNK / 2; ++pair) {
        const int c0 = 2 * pair, c1 = 2 * pair + 1;
        // prefetch c1 while reducing c0
#pragma unroll
        for (int d = 0; d < DENC; ++d)
            bufB[d] = *(const float2*)(cp + c1 * CHUNK + (size_t)d * NC);
        process(bufA, c0);
        // prefetch c0+2 while reducing c1
        if (pair < NCHUNK / 2 - 1) {
#pragma unroll
            for (int d = 0; d < DENC; ++d)
                bufA[d] = *(const float2*)(cp + (c0 + 2) * CHUNK + (size_t)d * NC);
        }
        process(bufB, c1);
    }

    // one butterfly for the 20 class sums
#pragma unroll
    for (int k = 0; k < 2 * DOUT; ++k) {
#pragma unroll
        for (int sh = 32; sh >= 1; sh >>= 1) cls[k] += __shfl_xor(cls[k], sh);
    }
    if (lane == 0) {
#pragma unroll
        for (int k = 0; k < 2 * DOUT; ++k) cls_parts[wave][k] = cls[k];
    }
    __syncthreads();

    // per-(q,chunk) lse: combine 8 wave partials exactly
    if (tid < 16) {
        int q = tid & 1, ch = tid >> 1;
        const float* p = ms_parts + ch * 32 + 2 * q;
        float M = INFINITY;
#pragma unroll
        for (int w = 0; w < 8; ++w) M = fminf(M, p[w * 4]);
        float S = 0.f;
#pragma unroll
        for (int w = 0; w < 8; ++w) S += __expf(M - p[w * 4]) * p[w * 4 + 1];
        tmp[q][ch] = logf(S) - M;     // log(sum_c exp(-d)) for this chunk
    }
    __syncthreads();
    if (tid < 2) {
        float l = 0.f;
#pragma unroll
        for (int ch = 0; ch < NCHUNK; ++ch) l += tmp[tid][ch];
        lse_sh[tid] = l;
    }
    __syncthreads();
    if (tid < 2 * DOUT) {
        int q = tid / DOUT, k = tid % DOUT;
        float s = 0.f;
#pragma unroll
        for (int w = 0; w < 8; ++w) s += cls_parts[w][q * DOUT + k];
        out[(q0 + q) * DOUT + k] = logf(s + 1e-8f) - lse_sh[q];
    }
}

extern "C" void kernel_launch(void* const* d_in, const int* in_sizes, int n_in,
                              void* d_out, int out_size, void* d_ws, size_t ws_size,
                              hipStream_t stream) {
    const float* x_num = (const float*)d_in[0];
    const float* x_cat = (const float*)d_in[1];
    const float* c_num = (const float*)d_in[2];
    const float* c_cat = (const float*)d_in[3];
    const int*   c_y   = (const int*)d_in[4];
    const float* delta = (const float*)d_in[5];
    const float* u     = (const float*)d_in[6];

    float* ws = (float*)d_ws;
    float* cEnc = ws;                             // 26*8000 = 208,000 floats
    float* qEnc = cEnc + (size_t)DENC * NC;       // 26*512  = 13,312

    const int total = (NC + NQ) * DENC;           // 221,312
    encode<<<(total + 255) / 256, 256, 0, stream>>>(
        c_num, c_cat, x_num, x_cat, delta, u, cEnc, qEnc);
    nca_all<<<NQ / 2, 512, 0, stream>>>(cEnc, qEnc, c_y, (float*)d_out);
}